// Round 1
// baseline (4107.351 us; speedup 1.0000x reference)
//
#include <hip/hip_runtime.h>
#include <hip/hip_bf16.h>
#include <math.h>

#define B_ 128
#define L_ 196
#define D_ 512
#define T_ 20
#define V_ 10000
#define E_ 256
#define H_ 512
#define A_ 512
#define TM1 19
#define ROWS (TM1*B_)      /* 2432 */
#define G4H 2048
#define KCAT 1024

__device__ __forceinline__ float fast_tanh(float x){
    float ax = fabsf(x);
    float e = __expf(-2.f*ax);
    float t = (1.f - e)/(1.f + e);
    return copysignf(t, x);
}
__device__ __forceinline__ float sigmoidf_(float x){ return 1.f/(1.f+__expf(-x)); }

// ---------------- generic f32 GEMM: C = act(A@B + bias + add) ----------------
template<int ACT>
__global__ __launch_bounds__(256) void gemm64(const float* __restrict__ A, int lda,
                       const float* __restrict__ Bm, int ldb,
                       float* __restrict__ C, int ldc,
                       int M, int N, int K,
                       const float* __restrict__ bias,
                       const float* __restrict__ add, int ldadd)
{
    __shared__ float As[16][65];
    __shared__ float Bs[16][65];
    int bm = blockIdx.y*64, bn = blockIdx.x*64;
    int tid = threadIdx.x;
    int tx = tid & 15, ty = tid >> 4;
    float acc[4][4] = {};
    for (int k0 = 0; k0 < K; k0 += 16) {
        {
            int r  = tid >> 2;          // 0..63
            int kq = (tid & 3) * 4;     // 0,4,8,12
            int row = bm + r;
            float4 va = make_float4(0.f,0.f,0.f,0.f);
            if (row < M) va = *(const float4*)(A + (size_t)row*lda + k0 + kq);
            As[kq+0][r]=va.x; As[kq+1][r]=va.y; As[kq+2][r]=va.z; As[kq+3][r]=va.w;
        }
        {
            int kk = tid >> 4;          // 0..15
            int nq = (tid & 15) * 4;    // 0..60
            int col = bn + nq;
            float4 vb = make_float4(0.f,0.f,0.f,0.f);
            if (col < N) vb = *(const float4*)(Bm + (size_t)(k0+kk)*ldb + col);
            Bs[kk][nq+0]=vb.x; Bs[kk][nq+1]=vb.y; Bs[kk][nq+2]=vb.z; Bs[kk][nq+3]=vb.w;
        }
        __syncthreads();
        #pragma unroll
        for (int k = 0; k < 16; ++k) {
            float a0[4], b0[4];
            #pragma unroll
            for (int i=0;i<4;i++) a0[i] = As[k][ty*4+i];
            #pragma unroll
            for (int j=0;j<4;j++) b0[j] = Bs[k][tx*4+j];
            #pragma unroll
            for (int i=0;i<4;i++)
                #pragma unroll
                for (int j=0;j<4;j++)
                    acc[i][j] = fmaf(a0[i], b0[j], acc[i][j]);
        }
        __syncthreads();
    }
    #pragma unroll
    for (int i=0;i<4;i++){
        int row = bm + ty*4 + i;
        if (row >= M) continue;
        #pragma unroll
        for (int j=0;j<4;j++){
            int col = bn + tx*4 + j;
            if (col >= N) continue;
            float vo = acc[i][j];
            if (bias) vo += bias[col];
            if (add)  vo += add[(size_t)row*ldadd + col];
            if (ACT==1) vo = fast_tanh(vo);
            C[(size_t)row*ldc + col] = vo;
        }
    }
}

// ---------------- prep: Whc=Wh+Wc, bias4h=b_ih+b_hh, Wcat=[W_ih[E:],W_hh] ----
__global__ void prep_k(const float* __restrict__ Wh, const float* __restrict__ Wc, float* __restrict__ Whc,
                       const float* __restrict__ b_ih, const float* __restrict__ b_hh, float* __restrict__ bias4h,
                       const float* __restrict__ W_ih, const float* __restrict__ W_hh, float* __restrict__ Wcat){
    int i = blockIdx.x*blockDim.x + threadIdx.x;
    if (i < H_*A_) Whc[i] = Wh[i] + Wc[i];
    if (i < G4H)   bias4h[i] = b_ih[i] + b_hh[i];
    if (i < KCAT*G4H){
        int r = i >> 11, n = i & 2047;
        Wcat[i] = (r < D_) ? W_ih[(size_t)(E_+r)*G4H + n] : W_hh[(size_t)(r-D_)*G4H + n];
    }
}

__global__ void mean_ctx_k(const float* __restrict__ a, float* __restrict__ mc){
    int idx = blockIdx.x*blockDim.x + threadIdx.x;   // b*512 + d
    int b = idx >> 9, d = idx & 511;
    const float* p = a + (size_t)b*L_*D_ + d;
    float s = 0.f;
    for (int l=0;l<L_;l++) s += p[(size_t)l*D_];
    mc[idx] = s * (1.f/(float)L_);
}

__global__ void gather_emb(const int* __restrict__ captions, const float* __restrict__ embW,
                           float* __restrict__ xemb){
    int i = blockIdx.x;                 // t*B + b
    int t = i / B_, b = i - t*B_;
    int cap = captions[b*T_ + t];
    const float* src = embW + (size_t)cap*E_;
    float* dst = xemb + (size_t)i*E_;
    for (int e = threadIdx.x; e < E_; e += blockDim.x) dst[e] = src[e];
}

// e[b,l] = sum_k tanh(wa[b,l,k] + hWh[b,k]) * v[k]   (one wave per (b,l))
__global__ __launch_bounds__(256) void attn_e_k(const float* __restrict__ wa, const float* __restrict__ hWh,
                         const float* __restrict__ v, float* __restrict__ e){
    int w = (blockIdx.x<<2) + (threadIdx.x>>6);
    int lane = threadIdx.x & 63;
    int b = w / L_;
    const float* pw = wa + (size_t)w*A_;
    const float* ph = hWh + (size_t)b*A_;
    float s = 0.f;
    #pragma unroll
    for (int kk = 0; kk < A_/64; ++kk){
        int k = lane + kk*64;
        s += fast_tanh(pw[k] + ph[k]) * v[k];
    }
    #pragma unroll
    for (int off=32; off; off>>=1) s += __shfl_down(s, off);
    if (lane==0) e[w] = s;
}

// per-b: softmax(e) -> alpha (store to out), beta=sigmoid(h.beta_W+b), ctx=beta*alpha@a -> xcat[:,0:512]
__global__ __launch_bounds__(256) void attn_ctx_k(const float* __restrict__ e, const float* __restrict__ a,
                           const float* __restrict__ beta_W, const float* __restrict__ beta_b,
                           float* __restrict__ xcat, float* __restrict__ alphas_out, int t)
{
    int b = blockIdx.x;
    int tid = threadIdx.x;
    __shared__ float sal[256];
    __shared__ float red[256];
    float ev = (tid < L_) ? e[b*L_ + tid] : -3.0e38f;
    red[tid] = ev; __syncthreads();
    for (int s=128; s>0; s>>=1){ if (tid<s) red[tid] = fmaxf(red[tid], red[tid+s]); __syncthreads(); }
    float m = red[0]; __syncthreads();
    float p = (tid < L_) ? __expf(ev - m) : 0.f;
    red[tid] = p; __syncthreads();
    for (int s=128; s>0; s>>=1){ if (tid<s) red[tid] += red[tid+s]; __syncthreads(); }
    float inv = 1.f/red[0]; __syncthreads();
    float al = p * inv;
    sal[tid] = al;
    if (tid < L_) alphas_out[(size_t)b*TM1*L_ + (size_t)t*L_ + tid] = al;
    // beta = sigmoid(h . beta_W + beta_b)
    const float* h = xcat + (size_t)b*KCAT + D_;
    float dv = h[tid]*beta_W[tid] + h[tid+256]*beta_W[tid+256];
    red[tid] = dv; __syncthreads();
    for (int s=128; s>0; s>>=1){ if (tid<s) red[tid] += red[tid+s]; __syncthreads(); }
    float beta = sigmoidf_(red[0] + beta_b[0]);
    __syncthreads();
    // ctx
    const float* ab = a + (size_t)b*L_*D_;
    float s0=0.f, s1=0.f;
    #pragma unroll 4
    for (int l=0; l<L_; ++l){
        float av = sal[l];
        s0 = fmaf(av, ab[(size_t)l*D_ + tid      ], s0);
        s1 = fmaf(av, ab[(size_t)l*D_ + tid + 256], s1);
    }
    xcat[(size_t)b*KCAT + tid      ] = beta*s0;
    xcat[(size_t)b*KCAT + tid + 256] = beta*s1;
}

__global__ __launch_bounds__(256) void lstm_k(const float* __restrict__ gates, float* __restrict__ cbuf,
                       float* __restrict__ xcat, float* __restrict__ Hall, int t){
    int idx = blockIdx.x*blockDim.x + threadIdx.x;   // b*H + j
    int b = idx >> 9, j = idx & 511;
    const float* g = gates + (size_t)b*G4H;
    float ig = sigmoidf_(g[j]);
    float fg = sigmoidf_(g[H_+j]);
    float gg = fast_tanh(g[2*H_+j]);
    float og = sigmoidf_(g[3*H_+j]);
    float c = fg * cbuf[idx] + ig * gg;
    float h = og * fast_tanh(c);
    cbuf[idx] = c;
    xcat[(size_t)b*KCAT + D_ + j] = h;
    Hall[(size_t)t*B_*H_ + idx] = h;
}

extern "C" void kernel_launch(void* const* d_in, const int* in_sizes, int n_in,
                              void* d_out, int out_size, void* d_ws, size_t ws_size,
                              hipStream_t stream) {
    const float* a      = (const float*)d_in[0];
    const int*   caps   = (const int*)  d_in[1];
    const float* embW   = (const float*)d_in[3];
    const float* Wa     = (const float*)d_in[4];
    const float* Wh     = (const float*)d_in[5];
    const float* Wc     = (const float*)d_in[6];
    const float* v      = (const float*)d_in[7];
    const float* beta_W = (const float*)d_in[8];
    const float* beta_b = (const float*)d_in[9];
    const float* W_ih   = (const float*)d_in[10];
    const float* W_hh   = (const float*)d_in[11];
    const float* b_ih   = (const float*)d_in[12];
    const float* b_hh   = (const float*)d_in[13];
    const float* fc_W   = (const float*)d_in[14];
    const float* fc_b   = (const float*)d_in[15];
    const float* iWh    = (const float*)d_in[16];
    const float* ibh    = (const float*)d_in[17];
    const float* iWc    = (const float*)d_in[18];
    const float* ibc    = (const float*)d_in[19];

    float* out    = (float*)d_out;
    float* wa     = out;                            // scratch: logits region, rewritten at end
    float* alphas = out + (size_t)ROWS*V_;

    float* ws = (float*)d_ws;
    float* mean_ctx = ws;  ws += 65536;
    float* cbuf     = ws;  ws += 65536;
    float* xcat     = ws;  ws += 131072;            // [ctx | h] per row
    float* hWhb     = ws;  ws += 65536;
    float* ebuf     = ws;  ws += 25088;
    float* Whc      = ws;  ws += 262144;
    float* Wcat     = ws;  ws += 2097152;
    float* bias4h   = ws;  ws += 2048;
    float* xemb     = ws;  ws += 622592;
    float* embWih   = ws;  ws += 4980736;
    float* Hall     = ws;  ws += 1245184;
    float* gates    = ws;  ws += 262144;

    prep_k<<<8192, 256, 0, stream>>>(Wh, Wc, Whc, b_ih, b_hh, bias4h, W_ih, W_hh, Wcat);
    mean_ctx_k<<<256, 256, 0, stream>>>(a, mean_ctx);
    gather_emb<<<ROWS, 256, 0, stream>>>(caps, embW, xemb);

    // h0 -> xcat[:,512:1024] ; c0 -> cbuf
    gemm64<1><<<dim3(8,2), 256, 0, stream>>>(mean_ctx, D_, iWh, H_, xcat+D_, KCAT, B_, H_, D_, ibh, nullptr, 0);
    gemm64<1><<<dim3(8,2), 256, 0, stream>>>(mean_ctx, D_, iWc, H_, cbuf, H_, B_, H_, D_, ibc, nullptr, 0);
    // wa = a @ Wa  (25088 x 512 x 512)
    gemm64<0><<<dim3(8,392), 256, 0, stream>>>(a, D_, Wa, A_, wa, A_, B_*L_, A_, D_, nullptr, nullptr, 0);
    // embWih = xemb @ W_ih[0:E,:] + (b_ih+b_hh)   (2432 x 2048 x 256)
    gemm64<0><<<dim3(32,38), 256, 0, stream>>>(xemb, E_, W_ih, G4H, embWih, G4H, ROWS, G4H, E_, bias4h, nullptr, 0);

    for (int t = 0; t < TM1; ++t){
        // hWh = h @ (Wh+Wc)    (prev_h == h identically in the reference scan)
        gemm64<0><<<dim3(8,2), 256, 0, stream>>>(xcat+D_, KCAT, Whc, A_, hWhb, A_, B_, A_, H_, nullptr, nullptr, 0);
        attn_e_k<<<6272, 256, 0, stream>>>(wa, hWhb, v, ebuf);
        attn_ctx_k<<<B_, 256, 0, stream>>>(ebuf, a, beta_W, beta_b, xcat, alphas, t);
        // gates = [ctx|h] @ Wcat + embWih[t]   (128 x 2048 x 1024)
        gemm64<0><<<dim3(32,2), 256, 0, stream>>>(xcat, KCAT, Wcat, G4H, gates, G4H, B_, G4H, KCAT,
                                                  nullptr, embWih + (size_t)t*B_*G4H, G4H);
        lstm_k<<<256, 256, 0, stream>>>(gates, cbuf, xcat, Hall, t);
    }
    // logits = Hall @ fc_W + fc_b   (2432 x 10000 x 512)
    gemm64<0><<<dim3(157,38), 256, 0, stream>>>(Hall, H_, fc_W, V_, out, V_, ROWS, V_, H_, fc_b, nullptr, 0);
}

// Round 2
// 1502.891 us; speedup vs baseline: 2.7330x; 2.7330x over previous
//
#include <hip/hip_runtime.h>
#include <hip/hip_bf16.h>
#include <math.h>

#define B_ 128
#define L_ 196
#define D_ 512
#define T_ 20
#define V_ 10000
#define E_ 256
#define H_ 512
#define A_ 512
#define TM1 19
#define ROWS (TM1*B_)      /* 2432 */
#define G4H 2048
#define KCAT 1024
#define VPAD 10112         /* 79*128 */

typedef __attribute__((ext_vector_type(8))) short bf16x8;
typedef __attribute__((ext_vector_type(4))) float f32x4;

__device__ __forceinline__ float fast_tanh(float x){
    float ax = fabsf(x);
    float e = __expf(-2.f*ax);
    float t = (1.f - e)/(1.f + e);
    return copysignf(t, x);
}
__device__ __forceinline__ float sigmoidf_(float x){ return 1.f/(1.f+__expf(-x)); }
__device__ __forceinline__ unsigned short f2b(float f){
    union{float f; unsigned u;} x; x.f = f;
    unsigned r = x.u + 0x7fffu + ((x.u>>16)&1u);
    return (unsigned short)(r>>16);
}
__device__ __forceinline__ float b2f(unsigned short h){
    union{unsigned u; float f;} x; x.u = ((unsigned)h)<<16;
    return x.f;
}

// ================= bf16 MFMA GEMM: C = A @ BT^T (+bias)(+add) =================
// A: [M][K] bf16 row-major (M % 128 == 0, K % 32 == 0)
// BT: [Npad][K] bf16 row-major (Npad = ceil(N/128)*128, rows >= N zero-filled)
// C: f32 or bf16 [M][ldc]
template<int OUT_BF16, int HAS_BIAS, int HAS_ADD>
__global__ __launch_bounds__(256)
void gemm_mfma(const unsigned short* __restrict__ A, int lda,
               const unsigned short* __restrict__ BT, int ldb,
               void* __restrict__ Cout, int ldc,
               int N, int K,
               const float* __restrict__ bias,
               const float* __restrict__ add, int ldadd)
{
    __shared__ unsigned short As[128*32];
    __shared__ unsigned short Bs[128*32];
    const int bm = blockIdx.y * 128;
    const int bn = blockIdx.x * 128;
    const int tid = threadIdx.x;
    const int lane = tid & 63;
    const int wave = tid >> 6;
    const int wm = (wave >> 1) * 64;
    const int wn = (wave & 1) * 64;
    const int lrow = lane & 15;
    const int lk8  = (lane >> 4) * 8;     // elements
    const int srow = tid >> 2;            // 0..63
    const int skq  = (tid & 3) * 8;       // 0,8,16,24

    f32x4 acc[4][4];
    #pragma unroll
    for (int i=0;i<4;i++)
        #pragma unroll
        for (int j=0;j<4;j++) acc[i][j] = (f32x4){0.f,0.f,0.f,0.f};

    const unsigned short* Abase = A  + (size_t)(bm+srow)*lda + skq;
    const unsigned short* Bbase = BT + (size_t)(bn+srow)*ldb + skq;

    for (int k0 = 0; k0 < K; k0 += 32) {
        int4 a0 = *(const int4*)(Abase + k0);
        int4 a1 = *(const int4*)(Abase + (size_t)64*lda + k0);
        int4 b0 = *(const int4*)(Bbase + k0);
        int4 b1 = *(const int4*)(Bbase + (size_t)64*ldb + k0);
        __syncthreads();
        *(int4*)&As[srow*32 + skq]      = a0;
        *(int4*)&As[(srow+64)*32 + skq] = a1;
        *(int4*)&Bs[srow*32 + skq]      = b0;
        *(int4*)&Bs[(srow+64)*32 + skq] = b1;
        __syncthreads();
        bf16x8 af[4], bfr[4];
        #pragma unroll
        for (int i=0;i<4;i++) af[i]  = *(bf16x8*)&As[(wm + i*16 + lrow)*32 + lk8];
        #pragma unroll
        for (int j=0;j<4;j++) bfr[j] = *(bf16x8*)&Bs[(wn + j*16 + lrow)*32 + lk8];
        #pragma unroll
        for (int i=0;i<4;i++)
            #pragma unroll
            for (int j=0;j<4;j++)
                acc[i][j] = __builtin_amdgcn_mfma_f32_16x16x32_bf16(af[i], bfr[j], acc[i][j], 0, 0, 0);
    }

    const int rq = (lane >> 4) * 4;
    #pragma unroll
    for (int j=0;j<4;j++){
        int col = bn + wn + j*16 + lrow;
        if (col >= N) continue;
        float bv = HAS_BIAS ? bias[col] : 0.f;
        #pragma unroll
        for (int i=0;i<4;i++){
            #pragma unroll
            for (int q=0;q<4;q++){
                int row = bm + wm + i*16 + rq + q;
                float v = acc[i][j][q] + bv;
                if (HAS_ADD) v += add[(size_t)row*ldadd + col];
                if (OUT_BF16) ((unsigned short*)Cout)[(size_t)row*ldc + col] = f2b(v);
                else          ((float*)Cout)[(size_t)row*ldc + col] = v;
            }
        }
    }
}

// ============ f32 tile GEMM (init path only): C = tanh(A@B + bias) ============
__global__ __launch_bounds__(256) void gemm64t(const float* __restrict__ A, int lda,
                       const float* __restrict__ Bm, int ldb,
                       float* __restrict__ C, int ldc,
                       int M, int N, int K, const float* __restrict__ bias)
{
    __shared__ float As[16][65];
    __shared__ float Bs[16][65];
    int bm = blockIdx.y*64, bn = blockIdx.x*64;
    int tid = threadIdx.x;
    int tx = tid & 15, ty = tid >> 4;
    float acc[4][4] = {};
    for (int k0 = 0; k0 < K; k0 += 16) {
        {
            int r  = tid >> 2;
            int kq = (tid & 3) * 4;
            float4 va = *(const float4*)(A + (size_t)(bm+r)*lda + k0 + kq);
            As[kq+0][r]=va.x; As[kq+1][r]=va.y; As[kq+2][r]=va.z; As[kq+3][r]=va.w;
        }
        {
            int kk = tid >> 4;
            int nq = (tid & 15) * 4;
            float4 vb = *(const float4*)(Bm + (size_t)(k0+kk)*ldb + bn + nq);
            Bs[kk][nq+0]=vb.x; Bs[kk][nq+1]=vb.y; Bs[kk][nq+2]=vb.z; Bs[kk][nq+3]=vb.w;
        }
        __syncthreads();
        #pragma unroll
        for (int k = 0; k < 16; ++k) {
            float a0[4], b0[4];
            #pragma unroll
            for (int i=0;i<4;i++) a0[i] = As[k][ty*4+i];
            #pragma unroll
            for (int j=0;j<4;j++) b0[j] = Bs[k][tx*4+j];
            #pragma unroll
            for (int i=0;i<4;i++)
                #pragma unroll
                for (int j=0;j<4;j++)
                    acc[i][j] = fmaf(a0[i], b0[j], acc[i][j]);
        }
        __syncthreads();
    }
    #pragma unroll
    for (int i=0;i<4;i++){
        int row = bm + ty*4 + i;
        #pragma unroll
        for (int j=0;j<4;j++){
            int col = bn + tx*4 + j;
            C[(size_t)row*ldc + col] = fast_tanh(acc[i][j] + bias[col]);
        }
    }
}

// ================= prep / convert kernels =================
// dst[n][koff+k] = bf16(src[k][n] (+ src2[k][n])), zero for n >= Nsz
__global__ void transpose_cvt(const float* __restrict__ src, const float* __restrict__ src2,
                              int lds_, int Ksz, int Nsz,
                              unsigned short* __restrict__ dst, int ldk, int koff)
{
    __shared__ float t[32][33];
    int n0 = blockIdx.x*32, k0 = blockIdx.y*32;
    int tx = threadIdx.x & 31, ty = threadIdx.x >> 5;   // 256 thr: ty 0..7
    #pragma unroll
    for (int kk = ty; kk < 32; kk += 8){
        int k = k0 + kk, n = n0 + tx;
        float v = 0.f;
        if (k < Ksz && n < Nsz){
            v = src[(size_t)k*lds_ + n];
            if (src2) v += src2[(size_t)k*lds_ + n];
        }
        t[kk][tx] = v;
    }
    __syncthreads();
    #pragma unroll
    for (int nn = ty; nn < 32; nn += 8){
        int n = n0 + nn, k = k0 + tx;
        if (k < Ksz) dst[(size_t)n*ldk + koff + k] = f2b(t[tx][nn]);
    }
}

__global__ void cvt_bf16_k(const float* __restrict__ src, unsigned short* __restrict__ dst){
    int i = (blockIdx.x*blockDim.x + threadIdx.x)*4;
    float4 v = *(const float4*)(src+i);
    unsigned short r[4] = {f2b(v.x),f2b(v.y),f2b(v.z),f2b(v.w)};
    *(uint2*)(dst+i) = *(uint2*)r;
}

__global__ void bias4h_k(const float* __restrict__ b_ih, const float* __restrict__ b_hh,
                         float* __restrict__ bias4h){
    int i = blockIdx.x*blockDim.x + threadIdx.x;
    bias4h[i] = b_ih[i] + b_hh[i];
}

__global__ void mean_ctx_k(const float* __restrict__ a, float* __restrict__ mc){
    int idx = blockIdx.x*blockDim.x + threadIdx.x;
    int b = idx >> 9, d = idx & 511;
    const float* p = a + (size_t)b*L_*D_ + d;
    float s = 0.f;
    for (int l=0;l<L_;l++) s += p[(size_t)l*D_];
    mc[idx] = s * (1.f/(float)L_);
}

__global__ void gather_emb(const int* __restrict__ captions, const float* __restrict__ embW,
                           unsigned short* __restrict__ xemb){
    int i = blockIdx.x;                 // t*B + b
    int t = i / B_, b = i - t*B_;
    int cap = captions[b*T_ + t];
    float4 v = ((const float4*)(embW + (size_t)cap*E_))[threadIdx.x];
    unsigned short r[4] = {f2b(v.x),f2b(v.y),f2b(v.z),f2b(v.w)};
    *(uint2*)(xemb + (size_t)i*E_ + threadIdx.x*4) = *(uint2*)r;
}

__global__ void cvt_h0_k(const float* __restrict__ h0f, unsigned short* __restrict__ xcat){
    int idx = blockIdx.x*blockDim.x + threadIdx.x;   // b*512 + j
    int b = idx >> 9, j = idx & 511;
    xcat[(size_t)b*KCAT + D_ + j] = f2b(h0f[idx]);
}

// ================= attention / lstm =================
// e[b,l] = sum_k tanh(wa_b[b,l,k] + hW[b,k]) * v[k]; one wave per (b,l)
__global__ __launch_bounds__(256) void attn_e_k(const unsigned short* __restrict__ wa,
                         const float* __restrict__ hW,
                         const float* __restrict__ v, float* __restrict__ e){
    int w = (blockIdx.x<<2) + (threadIdx.x>>6);
    int lane = threadIdx.x & 63;
    int b = w / L_;
    const unsigned short* pw = wa + (size_t)w*A_ + lane*8;
    const float* ph = hW + (size_t)b*A_ + lane*8;
    const float* pv = v + lane*8;
    int4 raw = *(const int4*)pw;
    unsigned short* pu = (unsigned short*)&raw;
    float4 h0 = *(const float4*)ph, h1 = *(const float4*)(ph+4);
    float4 v0 = *(const float4*)pv, v1 = *(const float4*)(pv+4);
    float s = 0.f;
    s += fast_tanh(b2f(pu[0]) + h0.x)*v0.x;
    s += fast_tanh(b2f(pu[1]) + h0.y)*v0.y;
    s += fast_tanh(b2f(pu[2]) + h0.z)*v0.z;
    s += fast_tanh(b2f(pu[3]) + h0.w)*v0.w;
    s += fast_tanh(b2f(pu[4]) + h1.x)*v1.x;
    s += fast_tanh(b2f(pu[5]) + h1.y)*v1.y;
    s += fast_tanh(b2f(pu[6]) + h1.z)*v1.z;
    s += fast_tanh(b2f(pu[7]) + h1.w)*v1.w;
    #pragma unroll
    for (int off=32; off; off>>=1) s += __shfl_down(s, off);
    if (lane==0) e[w] = s;
}

// grid (B,2): softmax + beta + ctx slice; writes alphas (y==0) and bf16 ctx into xcat
__global__ __launch_bounds__(256) void attn_ctx_k(const float* __restrict__ e, const unsigned short* __restrict__ a_b,
                           const float* __restrict__ beta_W, const float* __restrict__ beta_b,
                           unsigned short* __restrict__ xcat, float* __restrict__ alphas_out, int t)
{
    int b = blockIdx.x, dh = blockIdx.y;
    int tid = threadIdx.x;
    __shared__ float sal[256];
    __shared__ float red[256];
    float ev = (tid < L_) ? e[b*L_ + tid] : -3.0e38f;
    red[tid] = ev; __syncthreads();
    for (int s=128; s>0; s>>=1){ if (tid<s) red[tid] = fmaxf(red[tid], red[tid+s]); __syncthreads(); }
    float m = red[0]; __syncthreads();
    float p = (tid < L_) ? __expf(ev - m) : 0.f;
    red[tid] = p; __syncthreads();
    for (int s=128; s>0; s>>=1){ if (tid<s) red[tid] += red[tid+s]; __syncthreads(); }
    float al = p / red[0];
    __syncthreads();
    sal[tid] = al;
    if (dh==0 && tid < L_) alphas_out[(size_t)b*TM1*L_ + (size_t)t*L_ + tid] = al;
    const unsigned short* hb = xcat + (size_t)b*KCAT + D_;
    float dv = b2f(hb[tid])*beta_W[tid] + b2f(hb[tid+256])*beta_W[tid+256];
    red[tid] = dv; __syncthreads();
    for (int s=128; s>0; s>>=1){ if (tid<s) red[tid] += red[tid+s]; __syncthreads(); }
    float beta = sigmoidf_(red[0] + beta_b[0]);
    int d = dh*256 + tid;
    const unsigned short* pa = a_b + (size_t)b*L_*D_ + d;
    float s0 = 0.f;
    #pragma unroll 4
    for (int l=0; l<L_; ++l) s0 = fmaf(sal[l], b2f(pa[(size_t)l*D_]), s0);
    xcat[(size_t)b*KCAT + d] = f2b(beta*s0);
}

__global__ __launch_bounds__(256) void lstm_k(const float* __restrict__ gates, float* __restrict__ cbuf,
                       unsigned short* __restrict__ xcat, unsigned short* __restrict__ Hall, int t){
    int idx = blockIdx.x*blockDim.x + threadIdx.x;   // b*H + j
    int b = idx >> 9, j = idx & 511;
    const float* g = gates + (size_t)b*G4H;
    float ig = sigmoidf_(g[j]);
    float fg = sigmoidf_(g[H_+j]);
    float gg = fast_tanh(g[2*H_+j]);
    float og = sigmoidf_(g[3*H_+j]);
    float c = fg * cbuf[idx] + ig * gg;
    float h = og * fast_tanh(c);
    cbuf[idx] = c;
    unsigned short hb = f2b(h);
    xcat[(size_t)b*KCAT + D_ + j] = hb;
    Hall[(size_t)t*B_*H_ + idx] = hb;
}

extern "C" void kernel_launch(void* const* d_in, const int* in_sizes, int n_in,
                              void* d_out, int out_size, void* d_ws, size_t ws_size,
                              hipStream_t stream) {
    const float* a      = (const float*)d_in[0];
    const int*   caps   = (const int*)  d_in[1];
    const float* embW   = (const float*)d_in[3];
    const float* Wa     = (const float*)d_in[4];
    const float* Wh     = (const float*)d_in[5];
    const float* Wc     = (const float*)d_in[6];
    const float* v      = (const float*)d_in[7];
    const float* beta_W = (const float*)d_in[8];
    const float* beta_b = (const float*)d_in[9];
    const float* W_ih   = (const float*)d_in[10];
    const float* W_hh   = (const float*)d_in[11];
    const float* b_ih   = (const float*)d_in[12];
    const float* b_hh   = (const float*)d_in[13];
    const float* fc_W   = (const float*)d_in[14];
    const float* fc_b   = (const float*)d_in[15];
    const float* iWh    = (const float*)d_in[16];
    const float* ibh    = (const float*)d_in[17];
    const float* iWc    = (const float*)d_in[18];
    const float* ibc    = (const float*)d_in[19];

    float* out    = (float*)d_out;
    float* alphas = out + (size_t)ROWS*V_;

    // d_out scratch (dead before the final logits GEMM overwrites it):
    char* ob = (char*)d_out;
    unsigned short* wa_b   = (unsigned short*)(ob);                 // 25088*512*2  = 25,690,112
    unsigned short* a_b    = (unsigned short*)(ob + 25690112);      // 25,690,112
    float*          embWih = (float*)        (ob + 51380224);      // 2432*2048*4 = 19,922,944 (ends 71.3MB < 97.28MB)

    // d_ws layout (bytes)
    char* wb = (char*)d_ws;
    float* mean_ctx = (float*)(wb);             // 256KB
    float* cbuf     = (float*)(wb + 262144);    // 256KB
    float* h0f      = (float*)(wb + 524288);    // 256KB
    float* hW       = (float*)(wb + 786432);    // 256KB
    float* gates    = (float*)(wb + 1048576);   // 1MB
    float* ebuf     = (float*)(wb + 2097152);   // 128KB
    float* bias4h   = (float*)(wb + 2228224);   // 8KB
    unsigned short* xcat_b = (unsigned short*)(wb + 2236416);   // 256KB
    unsigned short* xemb_b = (unsigned short*)(wb + 2498560);   // 1.25MB
    unsigned short* Hall   = (unsigned short*)(wb + 3743744);   // 2.5MB
    unsigned short* WaT    = (unsigned short*)(wb + 6234112);   // 512KB
    unsigned short* WhcT   = (unsigned short*)(wb + 6758400);   // 512KB
    unsigned short* WihT   = (unsigned short*)(wb + 7282688);   // 1MB
    unsigned short* WcatT  = (unsigned short*)(wb + 8331264);   // 4MB
    unsigned short* fcWT   = (unsigned short*)(wb + 12525568);  // 10.36MB -> ends ~22.9MB

    // ---- prep ----
    bias4h_k<<<8, 256, 0, stream>>>(b_ih, b_hh, bias4h);
    transpose_cvt<<<dim3(16,16), 256, 0, stream>>>(Wa, nullptr, A_, D_, A_, WaT, 512, 0);
    transpose_cvt<<<dim3(16,16), 256, 0, stream>>>(Wh, Wc,      A_, H_, A_, WhcT, 512, 0);
    transpose_cvt<<<dim3(64,8),  256, 0, stream>>>(W_ih, nullptr, G4H, E_, G4H, WihT, 256, 0);
    transpose_cvt<<<dim3(64,16), 256, 0, stream>>>(W_ih + (size_t)E_*G4H, nullptr, G4H, D_, G4H, WcatT, KCAT, 0);
    transpose_cvt<<<dim3(64,16), 256, 0, stream>>>(W_hh, nullptr, G4H, H_, G4H, WcatT, KCAT, 512);
    transpose_cvt<<<dim3(316,16),256, 0, stream>>>(fc_W, nullptr, V_, H_, V_, fcWT, 512, 0);
    cvt_bf16_k<<<12544, 256, 0, stream>>>(a, a_b);
    mean_ctx_k<<<256, 256, 0, stream>>>(a, mean_ctx);
    gather_emb<<<ROWS, 64, 0, stream>>>(caps, embW, xemb_b);

    // h0 (f32+tanh) -> bf16 into xcat; c0 -> cbuf
    gemm64t<<<dim3(8,2), 256, 0, stream>>>(mean_ctx, D_, iWh, H_, h0f, H_, B_, H_, D_, ibh);
    gemm64t<<<dim3(8,2), 256, 0, stream>>>(mean_ctx, D_, iWc, H_, cbuf, H_, B_, H_, D_, ibc);
    cvt_h0_k<<<256, 256, 0, stream>>>(h0f, xcat_b);

    // wa_b = bf16(a @ Wa)    (25088 x 512 x 512)
    gemm_mfma<1,0,0><<<dim3(4,196), 256, 0, stream>>>(a_b, D_, WaT, D_, wa_b, A_, A_, D_, nullptr, nullptr, 0);
    // embWih = xemb @ W_ih[:E] + (b_ih+b_hh)   (2432 x 2048 x 256)
    gemm_mfma<0,1,0><<<dim3(16,19), 256, 0, stream>>>(xemb_b, E_, WihT, E_, embWih, G4H, G4H, E_, bias4h, nullptr, 0);

    for (int t = 0; t < TM1; ++t){
        // hW = h @ (Wh+Wc)   (prev_h == h in the reference scan)
        gemm_mfma<0,0,0><<<dim3(4,1), 256, 0, stream>>>(xcat_b + D_, KCAT, WhcT, H_, hW, A_, A_, H_, nullptr, nullptr, 0);
        attn_e_k<<<6272, 256, 0, stream>>>(wa_b, hW, v, ebuf);
        attn_ctx_k<<<dim3(B_,2), 256, 0, stream>>>(ebuf, a_b, beta_W, beta_b, xcat_b, alphas, t);
        // gates = [ctx|h] @ Wcat + embWih[t]   (128 x 2048 x 1024)
        gemm_mfma<0,0,1><<<dim3(16,1), 256, 0, stream>>>(xcat_b, KCAT, WcatT, KCAT, gates, G4H, G4H, KCAT,
                                                         nullptr, embWih + (size_t)t*B_*G4H, G4H);
        lstm_k<<<256, 256, 0, stream>>>(gates, cbuf, xcat_b, Hall, t);
    }
    // logits = Hall @ fc_W + fc_b   (2432 x 10000 x 512)
    gemm_mfma<0,1,0><<<dim3(79,19), 256, 0, stream>>>(Hall, H_, fcWT, H_, out, V_, V_, H_, fc_b, nullptr, 0);
}

// Round 3
// 1189.266 us; speedup vs baseline: 3.4537x; 1.2637x over previous
//
#include <hip/hip_runtime.h>
#include <hip/hip_bf16.h>
#include <math.h>

#define B_ 128
#define L_ 196
#define D_ 512
#define T_ 20
#define V_ 10000
#define E_ 256
#define H_ 512
#define A_ 512
#define TM1 19
#define ROWS (TM1*B_)      /* 2432 */
#define G4H 2048
#define KCAT 1024

typedef unsigned short ushort_t;
typedef __attribute__((ext_vector_type(8))) short bf16x8;
typedef __attribute__((ext_vector_type(4))) float f32x4;

__device__ __forceinline__ float fast_tanh(float x){
    float ax = fabsf(x);
    float e = __expf(-2.f*ax);
    float r = __builtin_amdgcn_rcpf(1.f + e);
    return copysignf((1.f - e)*r, x);
}
__device__ __forceinline__ float sigmoidf_(float x){
    return __builtin_amdgcn_rcpf(1.f + __expf(-x));
}
__device__ __forceinline__ ushort_t f2b(float f){
    union{float f; unsigned u;} x; x.f = f;
    unsigned r = x.u + 0x7fffu + ((x.u>>16)&1u);
    return (ushort_t)(r>>16);
}
__device__ __forceinline__ float b2f(ushort_t h){
    union{unsigned u; float f;} x; x.u = ((unsigned)h)<<16;
    return x.f;
}
__device__ __forceinline__ float b2f_lo(unsigned u){ union{unsigned u; float f;} x; x.u = u<<16; return x.f; }
__device__ __forceinline__ float b2f_hi(unsigned u){ union{unsigned u; float f;} x; x.u = u & 0xffff0000u; return x.f; }

// ================= bf16 MFMA GEMM: C = A @ BT^T (+bias) =================
// A: [M][K] bf16 (M%128==0, K%32==0); BT: [Npad][K] bf16 (rows>=N zeroed)
template<int OUT_BF16, int HAS_BIAS, int NT>
__global__ __launch_bounds__(256)
void gemm_mfma(const ushort_t* __restrict__ A, int lda,
               const ushort_t* __restrict__ BT, int ldb,
               void* __restrict__ Cout, int ldc,
               int N, int K, const float* __restrict__ bias)
{
    __shared__ ushort_t As[128*32];
    __shared__ ushort_t Bs[128*32];
    const int bm = blockIdx.y * 128;
    const int bn = blockIdx.x * 128;
    const int tid = threadIdx.x;
    const int lane = tid & 63;
    const int wave = tid >> 6;
    const int wm = (wave >> 1) * 64;
    const int wn = (wave & 1) * 64;
    const int lrow = lane & 15;
    const int lk8  = (lane >> 4) * 8;
    const int srow = tid >> 2;
    const int skq  = (tid & 3) * 8;

    f32x4 acc[4][4];
    #pragma unroll
    for (int i=0;i<4;i++)
        #pragma unroll
        for (int j=0;j<4;j++) acc[i][j] = (f32x4){0.f,0.f,0.f,0.f};

    const ushort_t* Abase = A  + (size_t)(bm+srow)*lda + skq;
    const ushort_t* Bbase = BT + (size_t)(bn+srow)*ldb + skq;

    for (int k0 = 0; k0 < K; k0 += 32) {
        int4 a0 = *(const int4*)(Abase + k0);
        int4 a1 = *(const int4*)(Abase + (size_t)64*lda + k0);
        int4 b0 = *(const int4*)(Bbase + k0);
        int4 b1 = *(const int4*)(Bbase + (size_t)64*ldb + k0);
        __syncthreads();
        *(int4*)&As[srow*32 + skq]      = a0;
        *(int4*)&As[(srow+64)*32 + skq] = a1;
        *(int4*)&Bs[srow*32 + skq]      = b0;
        *(int4*)&Bs[(srow+64)*32 + skq] = b1;
        __syncthreads();
        bf16x8 af[4], bfr[4];
        #pragma unroll
        for (int i=0;i<4;i++) af[i]  = *(bf16x8*)&As[(wm + i*16 + lrow)*32 + lk8];
        #pragma unroll
        for (int j=0;j<4;j++) bfr[j] = *(bf16x8*)&Bs[(wn + j*16 + lrow)*32 + lk8];
        #pragma unroll
        for (int i=0;i<4;i++)
            #pragma unroll
            for (int j=0;j<4;j++)
                acc[i][j] = __builtin_amdgcn_mfma_f32_16x16x32_bf16(af[i], bfr[j], acc[i][j], 0, 0, 0);
    }

    const int rq = (lane >> 4) * 4;
    #pragma unroll
    for (int j=0;j<4;j++){
        int col = bn + wn + j*16 + lrow;
        if (col >= N) continue;
        float bv = HAS_BIAS ? bias[col] : 0.f;
        #pragma unroll
        for (int i=0;i<4;i++){
            #pragma unroll
            for (int q=0;q<4;q++){
                int row = bm + wm + i*16 + rq + q;
                float v = acc[i][j][q] + bv;
                if (OUT_BF16) ((ushort_t*)Cout)[(size_t)row*ldc + col] = f2b(v);
                else if (NT)  __builtin_nontemporal_store(v, &((float*)Cout)[(size_t)row*ldc + col]);
                else          ((float*)Cout)[(size_t)row*ldc + col] = v;
            }
        }
    }
}

// ============ f32 tile GEMM (init path): C = tanh(A@B + bias) ============
__global__ __launch_bounds__(256) void gemm64t(const float* __restrict__ A, int lda,
                       const float* __restrict__ Bm, int ldb,
                       float* __restrict__ C, int ldc, const float* __restrict__ bias)
{
    __shared__ float As[16][65];
    __shared__ float Bs[16][65];
    int bm = blockIdx.y*64, bn = blockIdx.x*64;
    int tid = threadIdx.x;
    int tx = tid & 15, ty = tid >> 4;
    float acc[4][4] = {};
    for (int k0 = 0; k0 < D_; k0 += 16) {
        {
            int r  = tid >> 2;
            int kq = (tid & 3) * 4;
            float4 va = *(const float4*)(A + (size_t)(bm+r)*lda + k0 + kq);
            As[kq+0][r]=va.x; As[kq+1][r]=va.y; As[kq+2][r]=va.z; As[kq+3][r]=va.w;
        }
        {
            int kk = tid >> 4;
            int nq = (tid & 15) * 4;
            float4 vb = *(const float4*)(Bm + (size_t)(k0+kk)*ldb + bn + nq);
            Bs[kk][nq+0]=vb.x; Bs[kk][nq+1]=vb.y; Bs[kk][nq+2]=vb.z; Bs[kk][nq+3]=vb.w;
        }
        __syncthreads();
        #pragma unroll
        for (int k = 0; k < 16; ++k) {
            float a0[4], b0[4];
            #pragma unroll
            for (int i=0;i<4;i++) a0[i] = As[k][ty*4+i];
            #pragma unroll
            for (int j=0;j<4;j++) b0[j] = Bs[k][tx*4+j];
            #pragma unroll
            for (int i=0;i<4;i++)
                #pragma unroll
                for (int j=0;j<4;j++)
                    acc[i][j] = fmaf(a0[i], b0[j], acc[i][j]);
        }
        __syncthreads();
    }
    #pragma unroll
    for (int i=0;i<4;i++){
        int row = bm + ty*4 + i;
        #pragma unroll
        for (int j=0;j<4;j++){
            int col = bn + tx*4 + j;
            C[(size_t)row*ldc + col] = fast_tanh(acc[i][j] + bias[col]);
        }
    }
}

// ================= prep kernels =================
__global__ void transpose_cvt(const float* __restrict__ src, const float* __restrict__ src2,
                              int lds_, int Ksz, int Nsz,
                              ushort_t* __restrict__ dst, int ldk, int koff)
{
    __shared__ float t[32][33];
    int n0 = blockIdx.x*32, k0 = blockIdx.y*32;
    int tx = threadIdx.x & 31, ty = threadIdx.x >> 5;
    #pragma unroll
    for (int kk = ty; kk < 32; kk += 8){
        int k = k0 + kk, n = n0 + tx;
        float v = 0.f;
        if (k < Ksz && n < Nsz){
            v = src[(size_t)k*lds_ + n];
            if (src2) v += src2[(size_t)k*lds_ + n];
        }
        t[kk][tx] = v;
    }
    __syncthreads();
    #pragma unroll
    for (int nn = ty; nn < 32; nn += 8){
        int n = n0 + nn, k = k0 + tx;
        if (k < Ksz) dst[(size_t)n*ldk + koff + k] = f2b(t[tx][nn]);
    }
}

__global__ void bias4h_k(const float* __restrict__ b_ih, const float* __restrict__ b_hh,
                         float* __restrict__ bias4h){
    int i = blockIdx.x*blockDim.x + threadIdx.x;
    bias4h[i] = b_ih[i] + b_hh[i];
}

// one pass over a: column means + bf16 copy
__global__ __launch_bounds__(256) void mean_cvt_k(const float* __restrict__ a, ushort_t* __restrict__ a_b,
                                                  float* __restrict__ mc){
    int idx = blockIdx.x*256 + threadIdx.x;   // b*512 + d
    int b = idx >> 9, d = idx & 511;
    const float* p = a + (size_t)b*L_*D_ + d;
    ushort_t* q = a_b + (size_t)b*L_*D_ + d;
    float s = 0.f;
    for (int l=0;l<L_;l++){ float v = p[(size_t)l*D_]; s += v; q[(size_t)l*D_] = f2b(v); }
    mc[idx] = s * (1.f/(float)L_);
}

__global__ void gather_emb(const int* __restrict__ captions, const float* __restrict__ embW,
                           ushort_t* __restrict__ xemb){
    int i = blockIdx.x;                 // t*B + b
    int t = i / B_, b = i - t*B_;
    int cap = captions[b*T_ + t];
    float4 v = ((const float4*)(embW + (size_t)cap*E_))[threadIdx.x];
    ushort_t r[4] = {f2b(v.x),f2b(v.y),f2b(v.z),f2b(v.w)};
    *(uint2*)(xemb + (size_t)i*E_ + threadIdx.x*4) = *(uint2*)r;
}

__global__ void cvt_h0_k(const float* __restrict__ h0f, ushort_t* __restrict__ xcat){
    int idx = blockIdx.x*blockDim.x + threadIdx.x;   // b*512 + j
    int b = idx >> 9, j = idx & 511;
    xcat[(size_t)b*KCAT + D_ + j] = f2b(h0f[idx]);
}

// ================= hW via MFMA (h in A-row0 trick), shared by hw0 & lstm =================
__device__ __forceinline__ void hw_mfma_phase(const ushort_t* hls, const ushort_t* __restrict__ WhcT,
                                              float* __restrict__ hW, int b, int j){
    int lane = j & 63, wave = j >> 6;
    int wn = wave * 64;
    int col16 = lane & 15;
    int khi = (lane >> 4) * 8;
    bool a_on = (col16 == 0);
    f32x4 acc[4];
    #pragma unroll
    for (int f=0;f<4;f++) acc[f] = (f32x4){0.f,0.f,0.f,0.f};
    for (int kk=0; kk<16; kk++){
        bf16x8 af = (bf16x8){0,0,0,0,0,0,0,0};
        if (a_on) af = *(const bf16x8*)&hls[kk*32 + khi];
        #pragma unroll
        for (int f=0;f<4;f++){
            bf16x8 bf = *(const bf16x8*)(WhcT + (size_t)(wn + f*16 + col16)*512 + kk*32 + khi);
            acc[f] = __builtin_amdgcn_mfma_f32_16x16x32_bf16(af, bf, acc[f], 0, 0, 0);
        }
    }
    if (lane < 16){
        #pragma unroll
        for (int f=0;f<4;f++) hW[b*512 + wn + f*16 + lane] = acc[f][0];
    }
}

__global__ __launch_bounds__(512) void hw0_k(const ushort_t* __restrict__ xcat,
                                             const ushort_t* __restrict__ WhcT, float* __restrict__ hW){
    int b = blockIdx.x, j = threadIdx.x;
    __shared__ ushort_t hls[512];
    hls[j] = xcat[(size_t)b*KCAT + D_ + j];
    __syncthreads();
    hw_mfma_phase(hls, WhcT, hW, b, j);
}

// ================= loop kernels =================
// e[b,l] = sum_k tanh(wa[b,l,k] + hW[b,k]) * v[k];  grid (B,4) x 256
__global__ __launch_bounds__(256) void attn_e_k(const ushort_t* __restrict__ wa,
                         const float* __restrict__ hW,
                         const float* __restrict__ v, float* __restrict__ e){
    int b = blockIdx.x, quarter = blockIdx.y;
    int lane = threadIdx.x & 63, wave = threadIdx.x >> 6;
    const float* hp = hW + b*512 + lane*8;
    float4 hw0 = *(const float4*)hp;
    float4 hw1 = *(const float4*)(hp+4);
    const float* vp = v + lane*8;
    float4 v0 = *(const float4*)vp;
    float4 v1 = *(const float4*)(vp+4);
    int l0 = quarter*49;
    for (int r = l0 + wave; r < l0 + 49; r += 4){
        int4 raw = *(const int4*)(wa + (((size_t)(b*L_ + r))<<9) + lane*8);
        const unsigned* u = (const unsigned*)&raw;
        float s;
        s  = fast_tanh(b2f_lo(u[0]) + hw0.x)*v0.x;
        s += fast_tanh(b2f_hi(u[0]) + hw0.y)*v0.y;
        s += fast_tanh(b2f_lo(u[1]) + hw0.z)*v0.z;
        s += fast_tanh(b2f_hi(u[1]) + hw0.w)*v0.w;
        s += fast_tanh(b2f_lo(u[2]) + hw1.x)*v1.x;
        s += fast_tanh(b2f_hi(u[2]) + hw1.y)*v1.y;
        s += fast_tanh(b2f_lo(u[3]) + hw1.z)*v1.z;
        s += fast_tanh(b2f_hi(u[3]) + hw1.w)*v1.w;
        #pragma unroll
        for (int off=32; off; off>>=1) s += __shfl_down(s, off);
        if (lane==0) e[b*L_ + r] = s;
    }
}

// grid (B,2) x 128: softmax + beta + ctx(256 d's per block)
__global__ __launch_bounds__(128) void attn_ctx_k(const float* __restrict__ e, const ushort_t* __restrict__ a_b,
                           const float* __restrict__ beta_W, const float* __restrict__ beta_b,
                           ushort_t* __restrict__ xcat, float* __restrict__ alphas_out, int t)
{
    int b = blockIdx.x, dh = blockIdx.y;
    int tid = threadIdx.x;
    __shared__ float sal[L_];
    __shared__ float red[128];
    float e0 = e[b*L_ + tid];
    float e1 = (tid < L_-128) ? e[b*L_ + 128 + tid] : -3.0e38f;
    red[tid] = fmaxf(e0, e1); __syncthreads();
    #pragma unroll
    for (int s=64; s; s>>=1){ if (tid<s) red[tid] = fmaxf(red[tid], red[tid+s]); __syncthreads(); }
    float m = red[0]; __syncthreads();
    float p0 = __expf(e0 - m);
    float p1 = (tid < L_-128) ? __expf(e1 - m) : 0.f;
    red[tid] = p0 + p1; __syncthreads();
    #pragma unroll
    for (int s=64; s; s>>=1){ if (tid<s) red[tid] += red[tid+s]; __syncthreads(); }
    float inv = 1.f / red[0]; __syncthreads();
    sal[tid] = p0*inv;
    if (tid < L_-128) sal[128+tid] = p1*inv;
    if (dh==0){
        float* ap = alphas_out + (size_t)b*TM1*L_ + (size_t)t*L_;
        __builtin_nontemporal_store(p0*inv, ap + tid);
        if (tid < L_-128) __builtin_nontemporal_store(p1*inv, ap + 128 + tid);
    }
    // beta = sigmoid(h . beta_W + beta_b)
    const ushort_t* hb = xcat + (size_t)b*KCAT + D_ + 4*tid;
    uint2 hv = *(const uint2*)hb;
    float4 bw = *(const float4*)(beta_W + 4*tid);
    float dv = b2f_lo(hv.x)*bw.x + b2f_hi(hv.x)*bw.y + b2f_lo(hv.y)*bw.z + b2f_hi(hv.y)*bw.w;
    red[tid] = dv; __syncthreads();
    #pragma unroll
    for (int s=64; s; s>>=1){ if (tid<s) red[tid] += red[tid+s]; __syncthreads(); }
    float beta = sigmoidf_(red[0] + beta_b[0]);
    // ctx over 256 d's
    int d0 = dh*256 + 2*tid;
    const ushort_t* pa = a_b + (size_t)b*L_*D_ + d0;
    float s0 = 0.f, s1 = 0.f;
    #pragma unroll 4
    for (int l=0; l<L_; ++l){
        unsigned av = *(const unsigned*)(pa + ((size_t)l<<9));
        float al = sal[l];
        s0 = fmaf(al, b2f_lo(av), s0);
        s1 = fmaf(al, b2f_hi(av), s1);
    }
    unsigned pack = (unsigned)f2b(beta*s0) | (((unsigned)f2b(beta*s1))<<16);
    *(unsigned*)(xcat + (size_t)b*KCAT + d0) = pack;
}

// gates partials: grid (32, 4) x 256; tile M128 x N64, K-chunk 256
__global__ __launch_bounds__(256) void gates_k(const ushort_t* __restrict__ xcat,
                        const ushort_t* __restrict__ WcatT, float* __restrict__ gp){
    __shared__ ushort_t As[128*32];
    __shared__ ushort_t Bs[64*32];
    const int bn = blockIdx.x*64;
    const int ks = blockIdx.y;
    const int tid = threadIdx.x;
    const int lane = tid & 63, wave = tid >> 6;
    const int wm = wave*32;
    const int lrow = lane & 15;
    const int lk8 = (lane >> 4) * 8;
    f32x4 acc[2][4];
    #pragma unroll
    for (int i=0;i<2;i++)
        #pragma unroll
        for (int j=0;j<4;j++) acc[i][j] = (f32x4){0.f,0.f,0.f,0.f};

    const int arow0 = tid >> 1;            // 2 chunks per thread for A
    const int akq0  = (tid & 1) * 16;      // covers kq 0..15 / 16..31 in 2 int4? no: use c-scheme
    (void)arow0; (void)akq0;
    for (int kk = 0; kk < 8; ++kk){
        int k0 = ks*256 + kk*32;
        // A: 128 rows x 32k = 512 int4 chunks; thread does c=2tid, 2tid+1
        int c0 = 2*tid;
        int r0 = c0 >> 2,  kq0 = (c0 & 3)*8;
        int r1 = (c0+1) >> 2, kq1 = ((c0+1) & 3)*8;
        int4 a0 = *(const int4*)(xcat + (size_t)r0*KCAT + k0 + kq0);
        int4 a1 = *(const int4*)(xcat + (size_t)r1*KCAT + k0 + kq1);
        // B: 64 rows x 32k = 256 chunks; c = tid
        int rb = tid >> 2, kqb = (tid & 3)*8;
        int4 b0 = *(const int4*)(WcatT + (size_t)(bn+rb)*KCAT + k0 + kqb);
        __syncthreads();
        *(int4*)&As[r0*32 + kq0] = a0;
        *(int4*)&As[r1*32 + kq1] = a1;
        *(int4*)&Bs[rb*32 + kqb] = b0;
        __syncthreads();
        bf16x8 af[2], bfr[4];
        #pragma unroll
        for (int i=0;i<2;i++) af[i] = *(bf16x8*)&As[(wm + i*16 + lrow)*32 + lk8];
        #pragma unroll
        for (int j=0;j<4;j++) bfr[j] = *(bf16x8*)&Bs[(j*16 + lrow)*32 + lk8];
        #pragma unroll
        for (int i=0;i<2;i++)
            #pragma unroll
            for (int j=0;j<4;j++)
                acc[i][j] = __builtin_amdgcn_mfma_f32_16x16x32_bf16(af[i], bfr[j], acc[i][j], 0, 0, 0);
    }
    const int rq = (lane >> 4) * 4;
    #pragma unroll
    for (int i=0;i<2;i++){
        #pragma unroll
        for (int j=0;j<4;j++){
            int gcol = bn + j*16 + lrow;
            #pragma unroll
            for (int q=0;q<4;q++){
                int grow = wm + i*16 + rq + q;
                gp[((size_t)(ks*B_ + grow))*G4H + gcol] = acc[i][j][q];
            }
        }
    }
}

// lstm pointwise (+ksplit reduce) + next-step hW;  grid B_ x 512
__global__ __launch_bounds__(512) void lstm_hw_k(const float* __restrict__ gp, const float* __restrict__ embWih,
                       float* __restrict__ cbuf, ushort_t* __restrict__ xcat, ushort_t* __restrict__ Hall,
                       const ushort_t* __restrict__ WhcT, float* __restrict__ hW, int t){
    int b = blockIdx.x, j = threadIdx.x;
    __shared__ ushort_t hls[512];
    float gi, gf, gg, go;
    {
        const float* eb = embWih + ((size_t)(t*B_ + b))*G4H;
        gi = eb[j]; gf = eb[H_+j]; gg = eb[2*H_+j]; go = eb[3*H_+j];
    }
    #pragma unroll
    for (int ks=0; ks<4; ks++){
        const float* g = gp + ((size_t)(ks*B_ + b))*G4H;
        gi += g[j]; gf += g[H_+j]; gg += g[2*H_+j]; go += g[3*H_+j];
    }
    float ig = sigmoidf_(gi), fg = sigmoidf_(gf);
    float g2 = fast_tanh(gg), og = sigmoidf_(go);
    float c = fg*cbuf[b*H_+j] + ig*g2;
    float h = og*fast_tanh(c);
    cbuf[b*H_+j] = c;
    ushort_t hb = f2b(h);
    xcat[(size_t)b*KCAT + D_ + j] = hb;
    Hall[((size_t)t*B_ + b)*H_ + j] = hb;
    hls[j] = hb;
    __syncthreads();
    hw_mfma_phase(hls, WhcT, hW, b, j);
}

extern "C" void kernel_launch(void* const* d_in, const int* in_sizes, int n_in,
                              void* d_out, int out_size, void* d_ws, size_t ws_size,
                              hipStream_t stream) {
    const float* a      = (const float*)d_in[0];
    const int*   caps   = (const int*)  d_in[1];
    const float* embW   = (const float*)d_in[3];
    const float* Wa     = (const float*)d_in[4];
    const float* Wh     = (const float*)d_in[5];
    const float* Wc     = (const float*)d_in[6];
    const float* v      = (const float*)d_in[7];
    const float* beta_W = (const float*)d_in[8];
    const float* beta_b = (const float*)d_in[9];
    const float* W_ih   = (const float*)d_in[10];
    const float* W_hh   = (const float*)d_in[11];
    const float* b_ih   = (const float*)d_in[12];
    const float* b_hh   = (const float*)d_in[13];
    const float* fc_W   = (const float*)d_in[14];
    const float* fc_b   = (const float*)d_in[15];
    const float* iWh    = (const float*)d_in[16];
    const float* ibh    = (const float*)d_in[17];
    const float* iWc    = (const float*)d_in[18];
    const float* ibc    = (const float*)d_in[19];

    float* out    = (float*)d_out;
    float* alphas = out + (size_t)ROWS*V_;

    // d_out scratch (dead before final logits GEMM overwrites it)
    char* ob = (char*)d_out;
    ushort_t* wa_b   = (ushort_t*)(ob);               // 25,690,112 B
    ushort_t* a_b    = (ushort_t*)(ob + 25690112);    // 25,690,112 B
    float*    embWih = (float*)   (ob + 51380224);    // 19,922,944 B (ends 71.3MB < 97.28MB)

    // d_ws layout (byte offsets)
    char* wb = (char*)d_ws;
    float* mean_ctx = (float*)(wb);              // 262144
    float* cbuf     = (float*)(wb + 262144);     // 262144
    float* h0f      = (float*)(wb + 524288);     // 262144
    float* hWbuf    = (float*)(wb + 786432);     // 262144
    float* ebuf     = (float*)(wb + 1048576);    // 131072
    float* bias4h   = (float*)(wb + 1179648);    // 8192
    float* gp       = (float*)(wb + 1187840);    // 4194304
    ushort_t* xcat_b = (ushort_t*)(wb + 5382144);   // 262144
    ushort_t* xemb_b = (ushort_t*)(wb + 5644288);   // 1245184
    ushort_t* Hall   = (ushort_t*)(wb + 6889472);   // 2490368
    ushort_t* WaT    = (ushort_t*)(wb + 9379840);   // 524288
    ushort_t* WhcT   = (ushort_t*)(wb + 9904128);   // 524288
    ushort_t* WihT   = (ushort_t*)(wb + 10428416);  // 1048576
    ushort_t* WcatT  = (ushort_t*)(wb + 11476992);  // 4194304
    ushort_t* fcWT   = (ushort_t*)(wb + 15671296);  // 10354688 -> ends ~26MB

    // ---- prep ----
    bias4h_k<<<8, 256, 0, stream>>>(b_ih, b_hh, bias4h);
    transpose_cvt<<<dim3(16,16), 256, 0, stream>>>(Wa, nullptr, A_, D_, A_, WaT, 512, 0);
    transpose_cvt<<<dim3(16,16), 256, 0, stream>>>(Wh, Wc,      A_, H_, A_, WhcT, 512, 0);
    transpose_cvt<<<dim3(64,8),  256, 0, stream>>>(W_ih, nullptr, G4H, E_, G4H, WihT, 256, 0);
    transpose_cvt<<<dim3(64,16), 256, 0, stream>>>(W_ih + (size_t)E_*G4H, nullptr, G4H, D_, G4H, WcatT, KCAT, 0);
    transpose_cvt<<<dim3(64,16), 256, 0, stream>>>(W_hh, nullptr, G4H, H_, G4H, WcatT, KCAT, 512);
    transpose_cvt<<<dim3(316,16),256, 0, stream>>>(fc_W, nullptr, V_, H_, V_, fcWT, 512, 0);
    mean_cvt_k<<<256, 256, 0, stream>>>(a, a_b, mean_ctx);
    gather_emb<<<ROWS, 64, 0, stream>>>(caps, embW, xemb_b);

    gemm64t<<<dim3(8,2), 256, 0, stream>>>(mean_ctx, D_, iWh, H_, h0f, H_, ibh);
    gemm64t<<<dim3(8,2), 256, 0, stream>>>(mean_ctx, D_, iWc, H_, cbuf, H_, ibc);
    cvt_h0_k<<<256, 256, 0, stream>>>(h0f, xcat_b);
    hw0_k<<<B_, 512, 0, stream>>>(xcat_b, WhcT, hWbuf);

    // wa_b = bf16(a @ Wa)    (25088 x 512 x 512)
    gemm_mfma<1,0,0><<<dim3(4,196), 256, 0, stream>>>(a_b, D_, WaT, D_, wa_b, A_, A_, D_, nullptr);
    // embWih = xemb @ W_ih[:E] + (b_ih+b_hh)   (2432 x 2048 x 256)
    gemm_mfma<0,1,0><<<dim3(16,19), 256, 0, stream>>>(xemb_b, E_, WihT, E_, embWih, G4H, G4H, E_, bias4h);

    for (int t = 0; t < TM1; ++t){
        attn_e_k<<<dim3(B_,4), 256, 0, stream>>>(wa_b, hWbuf, v, ebuf);
        attn_ctx_k<<<dim3(B_,2), 128, 0, stream>>>(ebuf, a_b, beta_W, beta_b, xcat_b, alphas, t);
        gates_k<<<dim3(32,4), 256, 0, stream>>>(xcat_b, WcatT, gp);
        lstm_hw_k<<<B_, 512, 0, stream>>>(gp, embWih, cbuf, xcat_b, Hall, WhcT, hWbuf, t);
    }
    // logits = Hall @ fc_W + fc_b   (2432 x 10000 x 512), NT stores
    gemm_mfma<0,1,1><<<dim3(79,19), 256, 0, stream>>>(Hall, H_, fcWT, H_, out, V_, V_, H_, fc_b);
}